// Round 8
// baseline (11.513 us; speedup 1.0000x reference)
//
#include <hip/hip_runtime.h>
#include <hip/hip_bf16.h>

// Shapes (fixed by the reference):
//   input:       [B=32, S=2048, H=1024] float32
//   number_mask: [B=32, S=2048] int
//   max_number:  scalar 20 -> J = 20 labels (1..20)
//   output:      [B, J, 2H] float32
#define B_DIM 32
#define S_DIM 2048
#define H_DIM 1024
#define J_DIM 20

// FINAL: round-2 source verbatim — best measured (9.91 / 9.93 us, A/A-confirmed).
// One block of 256 per (b, j). Scalar coalesced mask scan (int4 variants all
// regressed: R3/R4/R5 = 11.8/17.7/17.5 us), wave shuffle reduce, two-barrier
// LDS-atomic combine (single-barrier variant measured equal, 10.2 us), then
// two coalesced float4 moves per thread. Zeros written when label absent
// (d_out is poisoned). Remaining time is launch/replay overhead: ideal data
// motion ~1.7 us vs 9.9 us measured.
__global__ __launch_bounds__(256) void aware_fused_kernel(
        const float* __restrict__ in,
        const int* __restrict__ mask,
        float* __restrict__ out) {
    const int bj    = blockIdx.x;        // b * J + j
    const int b     = bj / J_DIM;
    const int label = bj - b * J_DIM + 1;
    const int t     = threadIdx.x;       // 256 threads

    // --- scan mask row for first/last occurrence of `label` ---
    int lmin = S_DIM;
    int lmax = -1;
    const int* m = mask + (size_t)b * S_DIM;
    #pragma unroll
    for (int k = 0; k < S_DIM / 256; ++k) {
        int s = t + k * 256;
        int v = m[s];
        if (v == label) {
            lmin = min(lmin, s);
            lmax = max(lmax, s);
        }
    }
    // wave (64-lane) butterfly reduce
    #pragma unroll
    for (int off = 32; off > 0; off >>= 1) {
        lmin = min(lmin, __shfl_down(lmin, off, 64));
        lmax = max(lmax, __shfl_down(lmax, off, 64));
    }
    // combine 4 waves via LDS
    __shared__ int sf, sl;
    if (t == 0) { sf = S_DIM; sl = -1; }
    __syncthreads();
    if ((t & 63) == 0) {
        atomicMin(&sf, lmin);
        atomicMax(&sl, lmax);
    }
    __syncthreads();
    const int f = sf;
    const int l = sl;
    const bool exists = (f < S_DIM);

    // --- gather: H/4 = 256 float4 per half, one per thread ---
    float4* o = reinterpret_cast<float4*>(out + (size_t)bj * (2 * H_DIM));
    if (exists) {
        const float4* src_f = reinterpret_cast<const float4*>(
            in + ((size_t)b * S_DIM + f) * H_DIM);
        const float4* src_l = reinterpret_cast<const float4*>(
            in + ((size_t)b * S_DIM + l) * H_DIM);
        o[t]             = src_f[t];
        o[t + H_DIM / 4] = src_l[t];
    } else {
        float4 z; z.x = 0.f; z.y = 0.f; z.z = 0.f; z.w = 0.f;
        o[t]             = z;
        o[t + H_DIM / 4] = z;
    }
}

extern "C" void kernel_launch(void* const* d_in, const int* in_sizes, int n_in,
                              void* d_out, int out_size, void* d_ws, size_t ws_size,
                              hipStream_t stream) {
    const float* input = (const float*)d_in[0];
    const int*   mask  = (const int*)d_in[1];
    float*       out   = (float*)d_out;

    aware_fused_kernel<<<B_DIM * J_DIM, 256, 0, stream>>>(input, mask, out);
}